// Round 1
// baseline (199.821 us; speedup 1.0000x reference)
//
#include <hip/hip_runtime.h>

// FeatureFinetuningLoss: total = (1/C) * sum_{b,c} max(|m_bc - pos_c + eps| - |m_bc - neg_c + eps| + 1, 0)
// where m_bc = mean over 196 spatial elems of (qual[b]==1 ? feat : feat_p)[b,c,:,:],
// pos_c = avg_feat[label[b]][c], neg_c = avg_feat[1-label[b]][c].
// Memory-bound: only the SELECTED tensor per sample is read (~103 MB, not 205 MB).

#define B_ 128
#define C_ 1024
#define HW_ 196
#define NF4_ 49          // float4s per channel (784 B, 16B-aligned)
#define CPW_ 8           // channels per wave
#define WPB_ 4           // waves per block (256 threads)
#define CPB_ (CPW_*WPB_) // 32 channels per block
#define BLKS_PER_B_ (C_/CPB_) // 32
#define NBLOCKS_ (B_*BLKS_PER_B_) // 4096

__global__ __launch_bounds__(256) void loss_partial_kernel(
    const float* __restrict__ feat, const float* __restrict__ feat_p,
    const float* __restrict__ af, const int* __restrict__ qual,
    const int* __restrict__ label, float* __restrict__ ws)
{
    const int blk  = blockIdx.x;
    const int b    = blk >> 5;        // blk / 32
    const int cg   = blk & 31;        // channel group within sample
    const int wave = threadIdx.x >> 6;
    const int lane = threadIdx.x & 63;
    const int c0   = cg * CPB_ + wave * CPW_;

    const int q   = qual[b];
    const int lab = label[b];
    const float* base = (q == 1 ? feat : feat_p) + (size_t)b * (C_ * HW_);
    const float* pos_row = af + (size_t)lab * C_;
    const float* neg_row = af + (size_t)(1 - lab) * C_;

    float hacc = 0.0f;
    #pragma unroll
    for (int j = 0; j < CPW_; ++j) {
        const int c = c0 + j;
        const float4* p = (const float4*)(base + (size_t)c * HW_);
        float4 v = make_float4(0.f, 0.f, 0.f, 0.f);
        if (lane < NF4_) v = p[lane];           // one coalesced 784B load per wave
        float s = (v.x + v.y) + (v.z + v.w);
        #pragma unroll
        for (int off = 32; off > 0; off >>= 1)  // 64-lane butterfly
            s += __shfl_xor(s, off, 64);
        const float mean = s * (1.0f / 196.0f);
        const float pos = pos_row[c];           // same addr all lanes -> broadcast
        const float neg = neg_row[c];
        const float dap = fabsf(mean - pos + 1e-6f);
        const float dan = fabsf(mean - neg + 1e-6f);
        hacc += fmaxf(dap - dan + 1.0f, 0.0f);
    }

    __shared__ float sred[WPB_];
    if (lane == 0) sred[wave] = hacc;
    __syncthreads();
    if (threadIdx.x == 0) {
        ws[blk] = (sred[0] + sred[1]) + (sred[2] + sred[3]);
    }
}

__global__ __launch_bounds__(256) void final_reduce_kernel(
    const float* __restrict__ ws, float* __restrict__ out)
{
    const int tid = threadIdx.x;
    float s = 0.0f;
    #pragma unroll
    for (int i = 0; i < NBLOCKS_ / 256; ++i)
        s += ws[tid + i * 256];
    #pragma unroll
    for (int off = 32; off > 0; off >>= 1)
        s += __shfl_xor(s, off, 64);
    __shared__ float sred[WPB_];
    if ((tid & 63) == 0) sred[tid >> 6] = s;
    __syncthreads();
    if (tid == 0)
        out[0] = ((sred[0] + sred[1]) + (sred[2] + sred[3])) * (1.0f / (float)C_);
}

extern "C" void kernel_launch(void* const* d_in, const int* in_sizes, int n_in,
                              void* d_out, int out_size, void* d_ws, size_t ws_size,
                              hipStream_t stream) {
    const float* feat   = (const float*)d_in[0];
    const float* feat_p = (const float*)d_in[1];
    const float* af     = (const float*)d_in[2];   // (2, C)
    const int*   qual   = (const int*)d_in[3];
    const int*   label  = (const int*)d_in[4];
    float* out = (float*)d_out;
    float* ws  = (float*)d_ws;                     // NBLOCKS_ floats = 16 KB

    loss_partial_kernel<<<NBLOCKS_, 256, 0, stream>>>(feat, feat_p, af, qual, label, ws);
    final_reduce_kernel<<<1, 256, 0, stream>>>(ws, out);
}